// Round 3
// baseline (174.130 us; speedup 1.0000x reference)
//
#include <hip/hip_runtime.h>

// ChamferLoss: x,y [4, 8192, 3] fp32 -> scalar fp32.
// out = (sum_bn min_m d2 + sum_bm min_n d2) / 32768
//
// Round 3: (a) inline-asm v_pk_fma_f32 — round 2's float2 arithmetic was
// scalarized by the compiler (VALU busy 32us vs 13.6us ideal); (b) Q=2
// queries/lane -> 128 queries/block -> 512 blocks = 2 blocks/CU = 32
// waves/CU for latency hiding (round 2 had 1 block/CU, 40% VALUBusy).
// Pair-packed records from prep: v0={x0,x1,y0,y1}, v1={z0,z1,w0,w1}.

#define B_     4
#define N_     8192
#define PRB    4096         // pair-records per batch (N_/2)
#define NRECS  16384        // pair-records per side (B_*PRB)
#define FLT_BIG 3.0e38f

typedef float v2f __attribute__((ext_vector_type(2)));

static __device__ __forceinline__ v2f pk_fma(v2f a, v2f b, v2f c) {
    v2f d;
    asm("v_pk_fma_f32 %0, %1, %2, %3" : "=v"(d) : "v"(a), "v"(b), "v"(c));
    return d;
}

__global__ void zero_out_kernel(float* out) { *out = 0.0f; }

// 128 blocks x 256: one thread per pair-record (2 sides x 16384 records).
__global__ __launch_bounds__(256) void prep_kernel(
    const float* __restrict__ x, const float* __restrict__ y,
    float4* __restrict__ xrec, float4* __restrict__ yrec,
    float* __restrict__ out)
{
    int i = blockIdx.x * 256 + threadIdx.x;   // 0..32767
    if (i == 0) *out = 0.0f;
    int side = i >> 14;
    int r    = i & (NRECS - 1);
    const float* src = side ? y : x;
    float4*      dst = side ? yrec : xrec;
    const float* p = src + (size_t)r * 6;     // 2 adjacent points
    float p0x = p[0], p0y = p[1], p0z = p[2];
    float p1x = p[3], p1y = p[4], p1z = p[5];
    float w0 = fmaf(p0x, p0x, fmaf(p0y, p0y, p0z * p0z));
    float w1 = fmaf(p1x, p1x, fmaf(p1y, p1y, p1z * p1z));
    dst[2*r]   = make_float4(p0x, p1x, p0y, p1y);
    dst[2*r+1] = make_float4(p0z, p1z, w0, w1);
}

// 512 blocks x 1024. Block covers 128 queries (Q=2/lane); wave w sweeps
// 256 pair-records (512 points) of the opposite batch.
__global__ __launch_bounds__(1024, 8) void chamfer_kernel(
    const float* __restrict__ xraw, const float* __restrict__ yraw,
    const float4* __restrict__ xrec, const float4* __restrict__ yrec,
    float* __restrict__ out)
{
    __shared__ v2f red2[16][64];              // 8 KB per-wave partial mins

    const int tid  = threadIdx.x;
    const int wave = tid >> 6;
    const int lane = tid & 63;
    const int blk  = blockIdx.x;              // 0..511
    const bool xdir = (blk < 256);            // x queries vs y set
    const int b    = (blk & 255) >> 6;        // batch 0..3
    const int qofs = (blk & 63) << 7;         // query offset in batch

    const float*  qraw = xdir ? xraw : yraw;
    const float4* orec = xdir ? yrec : xrec;

    // Per-lane queries, pre-scaled by -2, splatted into v2f pairs.
    v2f qxm[2], qym[2], qzm[2];
    float acc[2];
    #pragma unroll
    for (int q = 0; q < 2; ++q) {
        int gq = b * N_ + qofs + lane * 2 + q;
        float ax = qraw[gq*3+0], ay = qraw[gq*3+1], az = qraw[gq*3+2];
        qxm[q] = (v2f){-2.0f*ax, -2.0f*ax};
        qym[q] = (v2f){-2.0f*ay, -2.0f*ay};
        qzm[q] = (v2f){-2.0f*az, -2.0f*az};
        acc[q] = FLT_BIG;
    }

    // Sweep: 256 records (512 points), wave-uniform broadcast loads.
    const float4* rp = orec + (size_t)2 * (b * PRB + wave * 256);
    #pragma unroll 4
    for (int k = 0; k < 256; ++k) {
        float4 u = rp[2*k];                   // {x0,x1,y0,y1}
        float4 v = rp[2*k+1];                 // {z0,z1,w0,w1}
        v2f px2 = (v2f){u.x, u.y};
        v2f py2 = (v2f){u.z, u.w};
        v2f pz2 = (v2f){v.x, v.y};
        v2f w2  = (v2f){v.z, v.w};
        #pragma unroll
        for (int q = 0; q < 2; ++q) {
            v2f t = pk_fma(qzm[q], pz2, w2);
            t = pk_fma(qym[q], py2, t);
            t = pk_fma(qxm[q], px2, t);
            acc[q] = fminf(acc[q], fminf(t.x, t.y));   // v_min3_f32
        }
    }

    red2[wave][lane] = (v2f){acc[0], acc[1]};
    __syncthreads();

    // Combine 16 wave-partials per query, add |q|^2, clamp, sum.
    if (tid < 128) {
        const float* red = (const float*)red2;     // red[w*128 + qlocal]
        float m = red[tid];
        #pragma unroll
        for (int w = 1; w < 16; ++w) m = fminf(m, red[w*128 + tid]);

        int gq = b * N_ + qofs + tid;
        float ax = qraw[gq*3+0], ay = qraw[gq*3+1], az = qraw[gq*3+2];
        float qn = fmaf(ax, ax, fmaf(ay, ay, az*az));
        float d2 = fmaxf(0.0f, qn + m);

        #pragma unroll
        for (int off = 32; off > 0; off >>= 1) d2 += __shfl_xor(d2, off);
        if ((tid & 63) == 0) atomicAdd(out, d2 * (1.0f / 32768.0f));
    }
}

// Fallback (ws too small): round-1 style raw-sweep kernel, known correct.
__global__ __launch_bounds__(1024) void chamfer_raw_kernel(
    const float* __restrict__ xraw, const float* __restrict__ yraw,
    float* __restrict__ out)
{
    __shared__ float4 red4[16][64];
    const int tid  = threadIdx.x;
    const int wave = tid >> 6;
    const int lane = tid & 63;
    const int blk  = blockIdx.x;
    const bool xdir = (blk < 128);
    const int b    = (blk & 127) >> 5;
    const int qofs = (blk & 31) << 8;
    const float* qraw = xdir ? xraw : yraw;
    const float* oraw = xdir ? yraw : xraw;

    float qx0[4], qx1[4], qx2[4], acc[4];
    #pragma unroll
    for (int q = 0; q < 4; ++q) {
        int gq = b * N_ + qofs + lane*4 + q;
        qx0[q] = qraw[gq*3+0]; qx1[q] = qraw[gq*3+1]; qx2[q] = qraw[gq*3+2];
        acc[q] = FLT_BIG;
    }
    const float* opp = oraw + (size_t)(b * N_ + wave * 512) * 3;
    #pragma unroll 4
    for (int k = 0; k < 512; ++k) {
        float p0 = opp[k*3+0], p1 = opp[k*3+1], p2 = opp[k*3+2];
        float w  = fmaf(p0, p0, fmaf(p1, p1, p2*p2));
        #pragma unroll
        for (int q = 0; q < 4; ++q) {
            float dot = qx0[q]*p0 + qx1[q]*p1 + qx2[q]*p2;
            acc[q] = fminf(acc[q], fmaf(-2.0f, dot, w));
        }
    }
    red4[wave][lane] = make_float4(acc[0], acc[1], acc[2], acc[3]);
    __syncthreads();
    if (tid < 256) {
        const float* red = (const float*)red4;
        float m = red[tid];
        #pragma unroll
        for (int w = 1; w < 16; ++w) m = fminf(m, red[w*256 + tid]);
        int gq = b * N_ + qofs + tid;
        float ax = qraw[gq*3+0], ay = qraw[gq*3+1], az = qraw[gq*3+2];
        float d2 = fmaxf(0.0f, fmaf(ax,ax,fmaf(ay,ay,az*az)) + m);
        #pragma unroll
        for (int off = 32; off > 0; off >>= 1) d2 += __shfl_xor(d2, off);
        if ((tid & 63) == 0) atomicAdd(out, d2 * (1.0f / 32768.0f));
    }
}

extern "C" void kernel_launch(void* const* d_in, const int* in_sizes, int n_in,
                              void* d_out, int out_size, void* d_ws, size_t ws_size,
                              hipStream_t stream)
{
    const float* x = (const float*)d_in[0];
    const float* y = (const float*)d_in[1];
    float* out = (float*)d_out;

    const size_t need = (size_t)2 * NRECS * 2 * sizeof(float4);   // 1 MiB
    if (ws_size >= need) {
        float4* xrec = (float4*)d_ws;
        float4* yrec = xrec + 2 * NRECS;
        prep_kernel<<<128, 256, 0, stream>>>(x, y, xrec, yrec, out);
        chamfer_kernel<<<512, 1024, 0, stream>>>(x, y, xrec, yrec, out);
    } else {
        zero_out_kernel<<<1, 1, 0, stream>>>(out);
        chamfer_raw_kernel<<<256, 1024, 0, stream>>>(x, y, out);
    }
}

// Round 4
// 97.077 us; speedup vs baseline: 1.7937x; 1.7937x over previous
//
#include <hip/hip_runtime.h>

// ChamferLoss: x,y [4, 8192, 3] fp32 -> scalar fp32.
// out = (sum_bn min_m d2 + sum_bm min_n d2) / 32768
//
// Round 4 theory: wave-uniform vector loads are NOT broadcast-free in the
// L1/TA path (~16 cyc per 64-lane dwordx4) -> rounds 1-3 were TCP-bound.
// Fix: stream opposite points through the SCALAR pipe (s_load_dwordx16,
// double-buffered, explicit lgkmcnt waits) and do guaranteed-packed math:
// v_pk_fma_f32 with op_sel cross-swap processes a 2-query x 2-point cell in
// 6 pk_fma + 2 v_min3 = 2.0 inst/pair. Queries held as pairs (-2 prescaled).
// S=4 sweep split; partial = relu(qn+min) combined via atomicMin on uint
// bits (relu commutes with min for the full-min); phase2 sums 65536 floats.

#define N_      8192
#define RPB     4096          // records (2 points) per batch
#define NRECS   16384         // records per side
#define NQ      65536         // total queries (2 sides)
#define FLT_BIG 3.0e38f

typedef float v2f  __attribute__((ext_vector_type(2)));
typedef unsigned int v16u __attribute__((ext_vector_type(16)));

__global__ void zero_out_kernel(float* out) { *out = 0.0f; }

// ---------------- prep: pack pair-records, init pmin/out ----------------
// record r of a side: dst[2r]={x0,x1,y0,y1}, dst[2r+1]={z0,z1,w0,w1}
__global__ __launch_bounds__(256) void prep_kernel(
    const float* __restrict__ x, const float* __restrict__ y,
    float4* __restrict__ xrec, float4* __restrict__ yrec,
    unsigned int* __restrict__ pmin, float* __restrict__ out)
{
    int i = blockIdx.x * 256 + threadIdx.x;   // 0..32767
    if (i == 0) *out = 0.0f;
    pmin[i]         = 0x7F800000u;            // +inf
    pmin[i + 32768] = 0x7F800000u;
    int side = i >> 14;
    int r    = i & (NRECS - 1);
    const float* src = side ? y : x;
    float4*      dst = side ? yrec : xrec;
    const float* p = src + (size_t)r * 6;
    float p0x = p[0], p0y = p[1], p0z = p[2];
    float p1x = p[3], p1y = p[4], p1z = p[5];
    float w0 = fmaf(p0x, p0x, fmaf(p0y, p0y, p0z * p0z));
    float w1 = fmaf(p1x, p1x, fmaf(p1y, p1y, p1z * p1z));
    dst[2*r]   = make_float4(p0x, p1x, p0y, p1y);
    dst[2*r+1] = make_float4(p0z, p1z, w0, w1);
}

// ---------------- main ----------------
// 512 blocks x 512 thr (8 waves). Block = (dir, batch, qgroup of 512
// queries, sweep-quarter). Wave sweeps 128 records via scalar loads.

static __device__ __forceinline__ void s_load2(v16u& a, v16u& b, const unsigned int* p) {
    asm volatile("s_load_dwordx16 %0, %2, 0x0\n\t"
                 "s_load_dwordx16 %1, %2, 0x40"
                 : "=s"(a), "=s"(b) : "s"(p));
}
static __device__ __forceinline__ void s_wait(v16u& a, v16u& b) {
    asm volatile("s_waitcnt lgkmcnt(0)" : "+s"(a), "+s"(b));
}

// one record (8 dwords in SGPRs) vs 4 query-pairs
static __device__ __forceinline__ void do_record(
    const unsigned int* d,                 // 8 uniform dwords
    const v2f* qx, const v2f* qy, const v2f* qz,  // 4 pairs each, -2 prescaled
    float* acc)                            // 8 accumulators
{
    v2f pxs = (v2f){__uint_as_float(d[0]), __uint_as_float(d[1])};
    v2f pys = (v2f){__uint_as_float(d[2]), __uint_as_float(d[3])};
    v2f pzs = (v2f){__uint_as_float(d[4]), __uint_as_float(d[5])};
    v2f w2v = (v2f){__uint_as_float(d[6]), __uint_as_float(d[7])};  // -> VGPR pair
    #pragma unroll
    for (int j = 0; j < 4; ++j) {
        v2f td, ts;
        // td = {q0*p0, q1*p1} chain; ts = {q0*p1, q1*p0} via op_sel swap
        asm("v_pk_fma_f32 %0, %1, %2, %3"
            : "=v"(td) : "v"(qz[j]), "s"(pzs), "v"(w2v));
        asm("v_pk_fma_f32 %0, %1, %2, %3 op_sel:[0,1,1] op_sel_hi:[1,0,0]"
            : "=v"(ts) : "v"(qz[j]), "s"(pzs), "v"(w2v));
        asm("v_pk_fma_f32 %0, %1, %2, %0"
            : "+v"(td) : "v"(qy[j]), "s"(pys));
        asm("v_pk_fma_f32 %0, %1, %2, %0 op_sel:[0,1,0] op_sel_hi:[1,0,1]"
            : "+v"(ts) : "v"(qy[j]), "s"(pys));
        asm("v_pk_fma_f32 %0, %1, %2, %0"
            : "+v"(td) : "v"(qx[j]), "s"(pxs));
        asm("v_pk_fma_f32 %0, %1, %2, %0 op_sel:[0,1,0] op_sel_hi:[1,0,1]"
            : "+v"(ts) : "v"(qx[j]), "s"(pxs));
        asm("v_min3_f32 %0, %0, %1, %2" : "+v"(acc[2*j])   : "v"(td.x), "v"(ts.x));
        asm("v_min3_f32 %0, %0, %1, %2" : "+v"(acc[2*j+1]) : "v"(td.y), "v"(ts.y));
    }
}

__global__ __launch_bounds__(512, 4) void chamfer_kernel(
    const float* __restrict__ xraw, const float* __restrict__ yraw,
    const float4* __restrict__ xrec, const float4* __restrict__ yrec,
    unsigned int* __restrict__ pmin)
{
    __shared__ float red[8 * 512];            // [wave][lane*8+q], 16 KB

    const int tid  = threadIdx.x;
    const int lane = tid & 63;
    const int wave = __builtin_amdgcn_readfirstlane(tid >> 6);
    const int blk  = blockIdx.x;              // 0..511
    const int dir   = blk >> 8;               // 0: x-queries vs y, 1: y vs x
    const int batch = (blk >> 6) & 3;
    const int qg    = (blk >> 2) & 15;
    const int seg   = blk & 3;

    const float*  qraw = dir ? yraw : xraw;
    const float4* orec = dir ? xrec : yrec;

    // ---- load this lane's 8 queries (contiguous 24 floats, 16B-aligned) ----
    const int qbase = batch * N_ + qg * 512;          // first query of block
    float f[24];
    {
        const float4* qv = (const float4*)(qraw + (size_t)qbase * 3) + lane * 6;
        #pragma unroll
        for (int k = 0; k < 6; ++k) {
            float4 t = qv[k];
            f[4*k] = t.x; f[4*k+1] = t.y; f[4*k+2] = t.z; f[4*k+3] = t.w;
        }
    }
    v2f qx[4], qy[4], qz[4];
    float acc[8];
    #pragma unroll
    for (int j = 0; j < 4; ++j) {
        qx[j] = (v2f){-2.0f * f[6*j+0], -2.0f * f[6*j+3]};
        qy[j] = (v2f){-2.0f * f[6*j+1], -2.0f * f[6*j+4]};
        qz[j] = (v2f){-2.0f * f[6*j+2], -2.0f * f[6*j+5]};
        acc[2*j] = FLT_BIG; acc[2*j+1] = FLT_BIG;
    }

    // ---- scalar-pipe sweep: 128 records, groups of 4 (2x dwordx16), dbuf ----
    const unsigned int* sp = (const unsigned int*)
        (orec + (size_t)2 * (batch * RPB + seg * 1024 + wave * 128));
    v16u a0, a1, b0, b1;
    s_load2(a0, a1, sp);
    for (int g = 0; g < 32; g += 2) {
        s_wait(a0, a1);
        if (g + 1 < 32) s_load2(b0, b1, sp + (g + 1) * 32);
        {
            unsigned int da[16], db[16];
            #pragma unroll
            for (int t = 0; t < 16; ++t) { da[t] = a0[t]; db[t] = a1[t]; }
            do_record(da,     qx, qy, qz, acc);
            do_record(da + 8, qx, qy, qz, acc);
            do_record(db,     qx, qy, qz, acc);
            do_record(db + 8, qx, qy, qz, acc);
        }
        s_wait(b0, b1);
        if (g + 2 < 32) s_load2(a0, a1, sp + (g + 2) * 32);
        {
            unsigned int da[16], db[16];
            #pragma unroll
            for (int t = 0; t < 16; ++t) { da[t] = b0[t]; db[t] = b1[t]; }
            do_record(da,     qx, qy, qz, acc);
            do_record(da + 8, qx, qy, qz, acc);
            do_record(db,     qx, qy, qz, acc);
            do_record(db + 8, qx, qy, qz, acc);
        }
    }

    // ---- block combine: 8 wave-partials per query ----
    #pragma unroll
    for (int j = 0; j < 8; ++j) red[wave * 512 + lane * 8 + j] = acc[j];
    __syncthreads();

    // thread t owns query (qbase + t); LDS addr w*512+t is conflict-free
    float m = red[tid];
    #pragma unroll
    for (int w = 1; w < 8; ++w) m = fminf(m, red[w * 512 + tid]);
    int gq = qbase + tid;
    float ax = qraw[gq*3+0], ay = qraw[gq*3+1], az = qraw[gq*3+2];
    float qn = fmaf(ax, ax, fmaf(ay, ay, az * az));
    float d2 = fmaxf(0.0f, qn + m);           // relu commutes with min
    atomicMin(&pmin[dir * 32768 + gq], __float_as_uint(d2));
}

// ---------------- phase 2: sum 65536 per-query d2 -> scalar ----------------
__global__ __launch_bounds__(256) void sum_kernel(
    const unsigned int* __restrict__ pmin, float* __restrict__ out)
{
    int i = blockIdx.x * 256 + threadIdx.x;   // 0..16383, 4 queries each
    float4 v = ((const float4*)pmin)[i];      // bits are valid non-neg floats
    float s = v.x + v.y + v.z + v.w;
    #pragma unroll
    for (int off = 32; off > 0; off >>= 1) s += __shfl_xor(s, off);
    if ((threadIdx.x & 63) == 0) atomicAdd(out, s * (1.0f / 32768.0f));
}

// ---------------- fallback (ws too small): round-1 kernel ----------------
__global__ __launch_bounds__(1024) void chamfer_raw_kernel(
    const float* __restrict__ xraw, const float* __restrict__ yraw,
    float* __restrict__ out)
{
    __shared__ float4 red4[16][64];
    const int tid  = threadIdx.x;
    const int wave = tid >> 6;
    const int lane = tid & 63;
    const int blk  = blockIdx.x;
    const bool xdir = (blk < 128);
    const int b    = (blk & 127) >> 5;
    const int qofs = (blk & 31) << 8;
    const float* qraw = xdir ? xraw : yraw;
    const float* oraw = xdir ? yraw : xraw;
    float qx0[4], qx1[4], qx2[4], acc[4];
    #pragma unroll
    for (int q = 0; q < 4; ++q) {
        int gq = b * N_ + qofs + lane*4 + q;
        qx0[q] = qraw[gq*3+0]; qx1[q] = qraw[gq*3+1]; qx2[q] = qraw[gq*3+2];
        acc[q] = FLT_BIG;
    }
    const float* opp = oraw + (size_t)(b * N_ + wave * 512) * 3;
    #pragma unroll 4
    for (int k = 0; k < 512; ++k) {
        float p0 = opp[k*3+0], p1 = opp[k*3+1], p2 = opp[k*3+2];
        float w  = fmaf(p0, p0, fmaf(p1, p1, p2*p2));
        #pragma unroll
        for (int q = 0; q < 4; ++q) {
            float dot = qx0[q]*p0 + qx1[q]*p1 + qx2[q]*p2;
            acc[q] = fminf(acc[q], fmaf(-2.0f, dot, w));
        }
    }
    red4[wave][lane] = make_float4(acc[0], acc[1], acc[2], acc[3]);
    __syncthreads();
    if (tid < 256) {
        const float* red = (const float*)red4;
        float m = red[tid];
        #pragma unroll
        for (int w = 1; w < 16; ++w) m = fminf(m, red[w*256 + tid]);
        int gq = b * N_ + qofs + tid;
        float ax = qraw[gq*3+0], ay = qraw[gq*3+1], az = qraw[gq*3+2];
        float d2 = fmaxf(0.0f, fmaf(ax,ax,fmaf(ay,ay,az*az)) + m);
        #pragma unroll
        for (int off = 32; off > 0; off >>= 1) d2 += __shfl_xor(d2, off);
        if ((tid & 63) == 0) atomicAdd(out, d2 * (1.0f / 32768.0f));
    }
}

extern "C" void kernel_launch(void* const* d_in, const int* in_sizes, int n_in,
                              void* d_out, int out_size, void* d_ws, size_t ws_size,
                              hipStream_t stream)
{
    const float* x = (const float*)d_in[0];
    const float* y = (const float*)d_in[1];
    float* out = (float*)d_out;

    // ws layout: [0,512K) xrec, [512K,1M) yrec, [1M,1.25M) pmin
    const size_t need = (size_t)NRECS * 2 * 2 * sizeof(float4) + NQ * 4;
    if (ws_size >= need) {
        float4* xrec = (float4*)d_ws;
        float4* yrec = xrec + 2 * NRECS;
        unsigned int* pmin = (unsigned int*)(yrec + 2 * NRECS);
        prep_kernel<<<128, 256, 0, stream>>>(x, y, xrec, yrec, pmin, out);
        chamfer_kernel<<<512, 512, 0, stream>>>(x, y, xrec, yrec, pmin);
        sum_kernel<<<64, 256, 0, stream>>>(pmin, out);
    } else {
        zero_out_kernel<<<1, 1, 0, stream>>>(out);
        chamfer_raw_kernel<<<256, 1024, 0, stream>>>(x, y, out);
    }
}